// Round 1
// baseline (401.966 us; speedup 1.0000x reference)
//
#include <hip/hip_runtime.h>
#include <hip/hip_bf16.h>

typedef __hip_bfloat16 bf16;
typedef float f32x4 __attribute__((ext_vector_type(4)));
typedef short bf16x8 __attribute__((ext_vector_type(8)));

#define DI __device__ __forceinline__

constexpr int B_ = 4, S_ = 2048, E_ = 1024, H_ = 16, D_ = 64;
constexpr int M_ = B_ * S_;              // 8192 rows in projection GEMMs
constexpr float SCALE = 0.03125f;        // 1/sqrt(1024)

DI unsigned short bfbits(float f) {
  __hip_bfloat16 h = __float2bfloat16(f);
  return *reinterpret_cast<unsigned short*>(&h);
}

// ---------------- cast f32 -> bf16, vectorized ----------------
__global__ __launch_bounds__(256) void cast_kernel(const float* __restrict__ src,
                                                   ushort* __restrict__ dst, int n4) {
  int i = blockIdx.x * 256 + threadIdx.x;
  if (i >= n4) return;
  float4 v = reinterpret_cast<const float4*>(src)[i];
  ushort4 o;
  o.x = bfbits(v.x); o.y = bfbits(v.y); o.z = bfbits(v.z); o.w = bfbits(v.w);
  reinterpret_cast<ushort4*>(dst)[i] = o;
}

DI void gload_lds16(const bf16* g, bf16* l) {
  __builtin_amdgcn_global_load_lds((const __attribute__((address_space(1))) void*)g,
                                   (__attribute__((address_space(3))) void*)l, 16, 0, 0);
}

// ---------------- projection GEMM: C = A(xb) @ W^T ----------------
// A [M_][E_] bf16 row-major, W [E_][E_] bf16 row-major ([n][k] = W^T input, NT GEMM)
// MODE 0/1: store [B,H,S,D]; MODE 2: store transposed [B,H,D,S]
template <int MODE>
__global__ __launch_bounds__(256) void gemm_qkv(const bf16* __restrict__ A,
                                                const bf16* __restrict__ W,
                                                bf16* __restrict__ dst) {
  constexpr int BM = 128, BN = 128, BK = 32;
  __shared__ __align__(16) bf16 As[BM * BK];
  __shared__ __align__(16) bf16 Bs[BN * BK];
  const int t = threadIdx.x;
  const int l = t & 63;
  const int w = t >> 6;
  const int wm = w >> 1, wn = w & 1;
  const int m0 = blockIdx.y * BM, n0 = blockIdx.x * BN;

  f32x4 acc[4][4] = {};

  for (int kt = 0; kt < E_ / BK; ++kt) {
    // stage A,B tiles: linear LDS dest, slot-XOR swizzled global source
    // LDS slot (r, sl) holds global k-block (sl ^ ((r>>1)&3)) of row r
#pragma unroll
    for (int i = 0; i < 2; ++i) {
      int t2 = i * 256 + t;
      int r = t2 >> 2, sl = t2 & 3;
      int g = sl ^ ((r >> 1) & 3);
      bf16* lbase = (bf16*)As + (size_t)(i * 256 + w * 64) * 8;  // wave-uniform
      gload_lds16(A + (size_t)(m0 + r) * E_ + kt * BK + g * 8, lbase);
      bf16* lbase2 = (bf16*)Bs + (size_t)(i * 256 + w * 64) * 8;
      gload_lds16(W + (size_t)(n0 + r) * E_ + kt * BK + g * 8, lbase2);
    }
    __syncthreads();
    bf16x8 af[4], bfr[4];
#pragma unroll
    for (int i = 0; i < 4; ++i) {
      int ra = wm * 64 + i * 16 + (l & 15);
      int sla = (l >> 4) ^ ((ra >> 1) & 3);
      af[i] = *reinterpret_cast<const bf16x8*>(As + (ra * 4 + sla) * 8);
      int rb = wn * 64 + i * 16 + (l & 15);
      int slb = (l >> 4) ^ ((rb >> 1) & 3);
      bfr[i] = *reinterpret_cast<const bf16x8*>(Bs + (rb * 4 + slb) * 8);
    }
#pragma unroll
    for (int i = 0; i < 4; ++i)
#pragma unroll
      for (int j = 0; j < 4; ++j)
        acc[i][j] = __builtin_amdgcn_mfma_f32_16x16x32_bf16(af[i], bfr[j], acc[i][j], 0, 0, 0);
    __syncthreads();
  }

  // epilogue: scatter into head-split layouts
#pragma unroll
  for (int i = 0; i < 4; ++i) {
#pragma unroll
    for (int j = 0; j < 4; ++j) {
#pragma unroll
      for (int jj = 0; jj < 4; ++jj) {
        int mr = m0 + wm * 64 + i * 16 + (l >> 4) * 4 + jj;
        int nc = n0 + wn * 64 + j * 16 + (l & 15);
        int b = mr >> 11, s = mr & 2047, h = nc >> 6, d = nc & 63;
        size_t idx;
        if (MODE == 2) idx = ((size_t)(b * H_ + h) * D_ + d) * S_ + s;   // V^T [B,H,D,S]
        else           idx = ((size_t)(b * H_ + h) * S_ + s) * D_ + d;   // [B,H,S,D]
        dst[idx] = __float2bfloat16(acc[i][j][jj]);
      }
    }
  }
}

// ---------------- flash attention ----------------
// grid (S/64, H, B); 256 threads = 4 waves; wave w owns 16 q-rows.
__global__ __launch_bounds__(256) void attn_kernel(const bf16* __restrict__ Q,
                                                   const bf16* __restrict__ K,
                                                   const bf16* __restrict__ Vt,
                                                   float* __restrict__ out) {
  constexpr int KT = 64;
  constexpr int LDK = 72;  // padded row stride (elems), 144B = 16B-aligned
  __shared__ __align__(16) bf16 Ks[KT * LDK];       // [kv][d]
  __shared__ __align__(16) bf16 Vs[D_ * LDK];       // [d][kv]  (from V^T global)
  __shared__ __align__(16) bf16 Ps[4 * 16 * LDK];   // per-wave P [16 q][kv]

  const int t = threadIdx.x;
  const int l = t & 63;
  const int w = t >> 6;
  const int h = blockIdx.y, b = blockIdx.z;
  const int q0 = blockIdx.x * 64 + w * 16;
  const size_t bh = (size_t)(b * H_ + h);
  const bf16* Qb = Q + bh * S_ * D_;
  const bf16* Kb = K + bh * S_ * D_;
  const bf16* Vb = Vt + bh * D_ * S_;

  // Q fragments held in registers for the whole KV sweep
  bf16x8 aq[2];
#pragma unroll
  for (int c = 0; c < 2; ++c)
    aq[c] = *reinterpret_cast<const bf16x8*>(Qb + (size_t)(q0 + (l & 15)) * D_ + c * 32 + (l >> 4) * 8);

  f32x4 o_acc[4] = {};
  float mt[4], lt[4];
#pragma unroll
  for (int jj = 0; jj < 4; ++jj) { mt[jj] = -1e30f; lt[jj] = 0.f; }

  for (int kt = 0; kt < S_ / KT; ++kt) {
    // stage K tile [64][64] and V^T tile [64 d][64 kv]
    {
      int r = t >> 3, c8 = (t & 7) * 8;  // r: 0..31, two halves
#pragma unroll
      for (int half = 0; half < 2; ++half) {
        int rr = r + half * 32;
        *reinterpret_cast<bf16x8*>(&Ks[rr * LDK + c8]) =
            *reinterpret_cast<const bf16x8*>(Kb + (size_t)(kt * KT + rr) * D_ + c8);
        *reinterpret_cast<bf16x8*>(&Vs[rr * LDK + c8]) =
            *reinterpret_cast<const bf16x8*>(Vb + (size_t)rr * S_ + kt * KT + c8);
      }
    }
    __syncthreads();

    // QK^T: D[q][kv], lane holds kv col (l&15)+16*nt, q rows (l>>4)*4+jj
    f32x4 sc[4] = {};
#pragma unroll
    for (int c = 0; c < 2; ++c) {
#pragma unroll
      for (int nt = 0; nt < 4; ++nt) {
        bf16x8 bk = *reinterpret_cast<const bf16x8*>(
            &Ks[(nt * 16 + (l & 15)) * LDK + c * 32 + (l >> 4) * 8]);
        sc[nt] = __builtin_amdgcn_mfma_f32_16x16x32_bf16(aq[c], bk, sc[nt], 0, 0, 0);
      }
    }
#pragma unroll
    for (int nt = 0; nt < 4; ++nt)
#pragma unroll
      for (int jj = 0; jj < 4; ++jj) sc[nt][jj] *= SCALE;

    // online softmax (row stats replicated across each 16-lane group)
    float mnew[4], alpha[4];
#pragma unroll
    for (int jj = 0; jj < 4; ++jj) {
      float mm = fmaxf(fmaxf(sc[0][jj], sc[1][jj]), fmaxf(sc[2][jj], sc[3][jj]));
      mm = fmaxf(mm, __shfl_xor(mm, 1));
      mm = fmaxf(mm, __shfl_xor(mm, 2));
      mm = fmaxf(mm, __shfl_xor(mm, 4));
      mm = fmaxf(mm, __shfl_xor(mm, 8));
      mnew[jj] = fmaxf(mt[jj], mm);
      alpha[jj] = __expf(mt[jj] - mnew[jj]);
      mt[jj] = mnew[jj];
    }
    float psum[4] = {0.f, 0.f, 0.f, 0.f};
#pragma unroll
    for (int nt = 0; nt < 4; ++nt)
#pragma unroll
      for (int jj = 0; jj < 4; ++jj) {
        float p = __expf(sc[nt][jj] - mnew[jj]);
        sc[nt][jj] = p;
        psum[jj] += p;
      }
#pragma unroll
    for (int jj = 0; jj < 4; ++jj) {
      float ps = psum[jj];
      ps += __shfl_xor(ps, 1);
      ps += __shfl_xor(ps, 2);
      ps += __shfl_xor(ps, 4);
      ps += __shfl_xor(ps, 8);
      lt[jj] = lt[jj] * alpha[jj] + ps;
#pragma unroll
      for (int nt = 0; nt < 4; ++nt) o_acc[nt][jj] *= alpha[jj];
    }

    // P -> LDS (layout fix-up for PV A-fragment), per-wave buffer
    bf16* Pw = &Ps[w * 16 * LDK];
#pragma unroll
    for (int nt = 0; nt < 4; ++nt)
#pragma unroll
      for (int jj = 0; jj < 4; ++jj)
        Pw[((l >> 4) * 4 + jj) * LDK + nt * 16 + (l & 15)] = __float2bfloat16(sc[nt][jj]);
    asm volatile("s_waitcnt lgkmcnt(0)" ::: "memory");

    // PV: O[q][d] += P[q][kv] V[kv][d]
#pragma unroll
    for (int c = 0; c < 2; ++c) {
      bf16x8 ap = *reinterpret_cast<const bf16x8*>(&Pw[(l & 15) * LDK + c * 32 + (l >> 4) * 8]);
#pragma unroll
      for (int nt = 0; nt < 4; ++nt) {
        bf16x8 bv = *reinterpret_cast<const bf16x8*>(
            &Vs[(nt * 16 + (l & 15)) * LDK + c * 32 + (l >> 4) * 8]);
        o_acc[nt] = __builtin_amdgcn_mfma_f32_16x16x32_bf16(ap, bv, o_acc[nt], 0, 0, 0);
      }
    }
    __syncthreads();
  }

  // epilogue: out [B,S,E] f32
#pragma unroll
  for (int nt = 0; nt < 4; ++nt)
#pragma unroll
    for (int jj = 0; jj < 4; ++jj) {
      int q = q0 + (l >> 4) * 4 + jj;
      int d = nt * 16 + (l & 15);
      out[((size_t)b * S_ + q) * E_ + h * D_ + d] = o_acc[nt][jj] / lt[jj];
    }
}

extern "C" void kernel_launch(void* const* d_in, const int* in_sizes, int n_in,
                              void* d_out, int out_size, void* d_ws, size_t ws_size,
                              hipStream_t stream) {
  const float* x = (const float*)d_in[0];
  const float* wq = (const float*)d_in[1];
  const float* wk = (const float*)d_in[2];
  const float* wv = (const float*)d_in[3];
  float* out = (float*)d_out;
  char* ws = (char*)d_ws;

  // workspace layout (bytes)
  bf16* xb  = (bf16*)(ws + 0);          // 16 MiB: [8192][1024]
  bf16* wqb = (bf16*)(ws + 16777216);   // 2 MiB
  bf16* wkb = (bf16*)(ws + 18874368);   // 2 MiB
  bf16* wvb = (bf16*)(ws + 20971520);   // 2 MiB
  bf16* Qh  = (bf16*)(ws + 23068672);   // 16 MiB [B,H,S,D]
  bf16* Kh  = (bf16*)(ws + 39845888);   // 16 MiB [B,H,S,D]
  bf16* Vth = (bf16*)(ws + 56623104);   // 16 MiB [B,H,D,S]
  // total 73,400,320 bytes

  cast_kernel<<<8192, 256, 0, stream>>>(x, (ushort*)xb, M_ * E_ / 4);
  cast_kernel<<<1024, 256, 0, stream>>>(wq, (ushort*)wqb, E_ * E_ / 4);
  cast_kernel<<<1024, 256, 0, stream>>>(wk, (ushort*)wkb, E_ * E_ / 4);
  cast_kernel<<<1024, 256, 0, stream>>>(wv, (ushort*)wvb, E_ * E_ / 4);

  dim3 gg(E_ / 128, M_ / 128);
  gemm_qkv<0><<<gg, 256, 0, stream>>>(xb, wqb, Qh);
  gemm_qkv<1><<<gg, 256, 0, stream>>>(xb, wkb, Kh);
  gemm_qkv<2><<<gg, 256, 0, stream>>>(xb, wvb, Vth);

  attn_kernel<<<dim3(S_ / 64, H_, B_), 256, 0, stream>>>(Qh, Kh, Vth, out);
}

// Round 2
// 303.639 us; speedup vs baseline: 1.3238x; 1.3238x over previous
//
#include <hip/hip_runtime.h>
#include <hip/hip_bf16.h>

typedef __hip_bfloat16 bf16;
typedef float f32x4 __attribute__((ext_vector_type(4)));
typedef short bf16x8 __attribute__((ext_vector_type(8)));

#define DI __device__ __forceinline__

constexpr int B_ = 4, S_ = 2048, E_ = 1024, H_ = 16, D_ = 64;
constexpr int M_ = B_ * S_;
constexpr float QSCALE = 0.03125f * 1.4426950408889634f;  // 1/sqrt(E) * log2(e)

DI unsigned short bfbits(float f) {
  __hip_bfloat16 h = __float2bfloat16(f);
  return *reinterpret_cast<unsigned short*>(&h);
}

DI void gload_lds16(const bf16* g, bf16* l) {
  __builtin_amdgcn_global_load_lds((const __attribute__((address_space(1))) void*)g,
                                   (__attribute__((address_space(3))) void*)l, 16, 0, 0);
}

// ---------------- fused cast f32->bf16 (x + 3 weights) ----------------
__global__ __launch_bounds__(256) void cast_all(const float* __restrict__ x,
                                                const float* __restrict__ wq,
                                                const float* __restrict__ wk,
                                                const float* __restrict__ wv,
                                                ushort* __restrict__ xb,
                                                ushort* __restrict__ wqb,
                                                ushort* __restrict__ wkb,
                                                ushort* __restrict__ wvb) {
  int id = blockIdx.x * 256 + threadIdx.x;
  const float* src; ushort* dst; int i;
  if (id < 2097152)      { src = x;  dst = xb;  i = id; }
  else if (id < 2359296) { src = wq; dst = wqb; i = id - 2097152; }
  else if (id < 2621440) { src = wk; dst = wkb; i = id - 2359296; }
  else                   { src = wv; dst = wvb; i = id - 2621440; }
  float4 v = reinterpret_cast<const float4*>(src)[i];
  ushort4 o;
  o.x = bfbits(v.x); o.y = bfbits(v.y); o.z = bfbits(v.z); o.w = bfbits(v.w);
  reinterpret_cast<ushort4*>(dst)[i] = o;
}

// ---------------- projection GEMM: C = A @ W^T (dbuf, 1 barrier/iter) ----------------
// MODE 0: Q, scaled by QSCALE, [B,H,S,D]; MODE 1: K [B,H,S,D]; MODE 2: V^T [B,H,D,S]
template <int MODE>
__global__ __launch_bounds__(256) void gemm_qkv(const bf16* __restrict__ A,
                                                const bf16* __restrict__ W,
                                                bf16* __restrict__ dst) {
  constexpr int BM = 128, BN = 128, BK = 32, NK = E_ / BK;
  __shared__ __align__(16) bf16 As[2][BM * BK];
  __shared__ __align__(16) bf16 Bs[2][BN * BK];
  const int t = threadIdx.x;
  const int l = t & 63;
  const int w = t >> 6;
  const int wm = w >> 1, wn = w & 1;
  const int m0 = blockIdx.y * BM, n0 = blockIdx.x * BN;

  f32x4 acc[4][4] = {};

  auto stage = [&](int buf, int kt) {
#pragma unroll
    for (int i = 0; i < 2; ++i) {
      int t2 = i * 256 + t;
      int r = t2 >> 2, sl = t2 & 3;
      int g = sl ^ ((r >> 1) & 3);
      gload_lds16(A + (size_t)(m0 + r) * E_ + kt * BK + g * 8,
                  &As[buf][(size_t)(i * 256 + w * 64) * 8]);
      gload_lds16(W + (size_t)(n0 + r) * E_ + kt * BK + g * 8,
                  &Bs[buf][(size_t)(i * 256 + w * 64) * 8]);
    }
  };

  stage(0, 0);
  int cur = 0;
  for (int kt = 0; kt < NK; ++kt) {
    __syncthreads();  // drains vmcnt (staged tile ready) + protects overwrite
    if (kt + 1 < NK) stage(cur ^ 1, kt + 1);
    bf16x8 af[4], bfr[4];
#pragma unroll
    for (int i = 0; i < 4; ++i) {
      int ra = wm * 64 + i * 16 + (l & 15);
      int sla = (l >> 4) ^ ((ra >> 1) & 3);
      af[i] = *reinterpret_cast<const bf16x8*>(&As[cur][(ra * 4 + sla) * 8]);
      int rb = wn * 64 + i * 16 + (l & 15);
      int slb = (l >> 4) ^ ((rb >> 1) & 3);
      bfr[i] = *reinterpret_cast<const bf16x8*>(&Bs[cur][(rb * 4 + slb) * 8]);
    }
#pragma unroll
    for (int i = 0; i < 4; ++i)
#pragma unroll
      for (int j = 0; j < 4; ++j)
        acc[i][j] = __builtin_amdgcn_mfma_f32_16x16x32_bf16(af[i], bfr[j], acc[i][j], 0, 0, 0);
    cur ^= 1;
  }

  const float oscale = (MODE == 0) ? QSCALE : 1.0f;
#pragma unroll
  for (int i = 0; i < 4; ++i)
#pragma unroll
    for (int j = 0; j < 4; ++j)
#pragma unroll
      for (int jj = 0; jj < 4; ++jj) {
        int mr = m0 + wm * 64 + i * 16 + (l >> 4) * 4 + jj;
        int nc = n0 + wn * 64 + j * 16 + (l & 15);
        int b = mr >> 11, s = mr & 2047, h = nc >> 6, d = nc & 63;
        size_t idx;
        if (MODE == 2) idx = ((size_t)(b * H_ + h) * D_ + d) * S_ + s;  // V^T [B,H,D,S]
        else           idx = ((size_t)(b * H_ + h) * S_ + s) * D_ + d;  // [B,H,S,D]
        dst[idx] = __float2bfloat16(acc[i][j][jj] * oscale);
      }
}

// ---------------- flash attention (fixed-max softmax, dbuf, XOR-swizzled LDS) ----
// 1D grid 2048 with XCD-chunk swizzle; 256 thr = 4 waves; wave owns 16 q-rows.
__global__ __launch_bounds__(256) void attn_kernel(const bf16* __restrict__ Q,
                                                   const bf16* __restrict__ K,
                                                   const bf16* __restrict__ Vt,
                                                   float* __restrict__ out) {
  constexpr int KT = 64, NT = S_ / KT;
  __shared__ __align__(16) bf16 Ks[2][KT * D_];   // [kv][d], col-block XOR row&7
  __shared__ __align__(16) bf16 Vs[2][D_ * KT];   // [d][kv], col-block XOR row&7
  __shared__ __align__(16) bf16 Ps[4][16 * KT];   // per-wave P [q][kv], swizzled

  const int t = threadIdx.x, l = t & 63, w = t >> 6;
  const int hi = l >> 4, r15 = l & 15;
  const int p = blockIdx.x;
  const int lg = (p & 7) * 256 + (p >> 3);        // XCD-chunked (2048 = 8*256)
  const int qblk = lg & 31, h = (lg >> 5) & 15, b = lg >> 9;
  const int q0 = qblk * 64 + w * 16;
  const size_t bh = (size_t)(b * H_ + h);
  const bf16* Qb = Q + bh * S_ * D_;
  const bf16* Kb = K + bh * S_ * D_;
  const bf16* Vb = Vt + bh * D_ * S_;

  // Q fragments in registers (Q pre-scaled by QSCALE at GEMM epilogue)
  bf16x8 aq[2];
#pragma unroll
  for (int c = 0; c < 2; ++c)
    aq[c] = *reinterpret_cast<const bf16x8*>(Qb + (size_t)(q0 + r15) * D_ + c * 32 + hi * 8);

  f32x4 o_acc[4] = {};
  float lsum[4] = {0.f, 0.f, 0.f, 0.f};

  auto stage = [&](int buf, int kt) {
    const bf16* Kt_ = Kb + (size_t)kt * KT * D_;
    const bf16* Vt_ = Vb + kt * KT;
#pragma unroll
    for (int i = 0; i < 2; ++i) {
      int idx = i * 256 + t;
      int rr = idx >> 3, s = idx & 7;
      int g = s ^ (rr & 7);  // inverse-swizzled global source, linear LDS dest
      gload_lds16(Kt_ + rr * D_ + g * 8, &Ks[buf][(i * 256 + w * 64) * 8]);
      gload_lds16(Vt_ + (size_t)rr * S_ + g * 8, &Vs[buf][(i * 256 + w * 64) * 8]);
    }
  };

  stage(0, 0);
  int cur = 0;
  for (int kt = 0; kt < NT; ++kt) {
    __syncthreads();  // drains vmcnt: staged KV ready; prev reads done
    if (kt + 1 < NT) stage(cur ^ 1, kt + 1);

    // QK^T: lane holds q rows 4*hi+jj, kv col nt*16+r15 (scores pre-scaled via Q)
    f32x4 sc[4] = {};
#pragma unroll
    for (int c = 0; c < 2; ++c)
#pragma unroll
      for (int nt = 0; nt < 4; ++nt) {
        int r = nt * 16 + r15;
        bf16x8 bk = *reinterpret_cast<const bf16x8*>(
            &Ks[cur][r * D_ + (((4 * c + hi) ^ (r & 7)) * 8)]);
        sc[nt] = __builtin_amdgcn_mfma_f32_16x16x32_bf16(aq[c], bk, sc[nt], 0, 0, 0);
      }

    // fixed-max softmax: p = 2^s (safe: |s·log2e| << 80), per-lane partial sums
    bf16* Pw = Ps[w];
#pragma unroll
    for (int nt = 0; nt < 4; ++nt)
#pragma unroll
      for (int jj = 0; jj < 4; ++jj) {
        float pf = __builtin_amdgcn_exp2f(sc[nt][jj]);
        lsum[jj] += pf;
        int q = hi * 4 + jj;
        int blk = 2 * nt + (r15 >> 3);
        Pw[q * KT + ((blk ^ (q & 7)) * 8) + (r15 & 7)] = __float2bfloat16(pf);
      }
    asm volatile("s_waitcnt lgkmcnt(0)" ::: "memory");

    // PV: O[q][d] += P[q][kv] V^T[d][kv]
#pragma unroll
    for (int c = 0; c < 2; ++c) {
      bf16x8 ap = *reinterpret_cast<const bf16x8*>(
          &Pw[r15 * KT + (((4 * c + hi) ^ (r15 & 7)) * 8)]);
#pragma unroll
      for (int nt = 0; nt < 4; ++nt) {
        int d = nt * 16 + r15;
        bf16x8 bv = *reinterpret_cast<const bf16x8*>(
            &Vs[cur][d * KT + (((4 * c + hi) ^ (d & 7)) * 8)]);
        o_acc[nt] = __builtin_amdgcn_mfma_f32_16x16x32_bf16(ap, bv, o_acc[nt], 0, 0, 0);
      }
    }
    cur ^= 1;
  }

  // one-time row-sum reduction over the 16-lane column group
#pragma unroll
  for (int jj = 0; jj < 4; ++jj) {
    float s = lsum[jj];
    s += __shfl_xor(s, 1);
    s += __shfl_xor(s, 2);
    s += __shfl_xor(s, 4);
    s += __shfl_xor(s, 8);
    lsum[jj] = 1.f / s;
  }
#pragma unroll
  for (int nt = 0; nt < 4; ++nt)
#pragma unroll
    for (int jj = 0; jj < 4; ++jj) {
      int q = q0 + hi * 4 + jj;
      int d = nt * 16 + r15;
      out[((size_t)b * S_ + q) * E_ + h * D_ + d] = o_acc[nt][jj] * lsum[jj];
    }
}

extern "C" void kernel_launch(void* const* d_in, const int* in_sizes, int n_in,
                              void* d_out, int out_size, void* d_ws, size_t ws_size,
                              hipStream_t stream) {
  const float* x = (const float*)d_in[0];
  const float* wq = (const float*)d_in[1];
  const float* wk = (const float*)d_in[2];
  const float* wv = (const float*)d_in[3];
  float* out = (float*)d_out;
  char* ws = (char*)d_ws;

  bf16* xb  = (bf16*)(ws + 0);          // 16 MiB [8192][1024]
  bf16* wqb = (bf16*)(ws + 16777216);   // 2 MiB
  bf16* wkb = (bf16*)(ws + 18874368);   // 2 MiB
  bf16* wvb = (bf16*)(ws + 20971520);   // 2 MiB
  bf16* Qh  = (bf16*)(ws + 23068672);   // 16 MiB [B,H,S,D] (pre-scaled)
  bf16* Kh  = (bf16*)(ws + 39845888);   // 16 MiB [B,H,S,D]
  bf16* Vth = (bf16*)(ws + 56623104);   // 16 MiB [B,H,D,S]

  cast_all<<<11264, 256, 0, stream>>>(x, wq, wk, wv, (ushort*)xb, (ushort*)wqb,
                                      (ushort*)wkb, (ushort*)wvb);

  dim3 gg(E_ / 128, M_ / 128);
  gemm_qkv<0><<<gg, 256, 0, stream>>>(xb, wqb, Qh);
  gemm_qkv<1><<<gg, 256, 0, stream>>>(xb, wkb, Kh);
  gemm_qkv<2><<<gg, 256, 0, stream>>>(xb, wvb, Vth);

  attn_kernel<<<2048, 256, 0, stream>>>(Qh, Kh, Vth, out);
}

// Round 3
// 278.724 us; speedup vs baseline: 1.4422x; 1.0894x over previous
//
#include <hip/hip_runtime.h>
#include <hip/hip_bf16.h>

typedef __hip_bfloat16 bf16;
typedef float f32x4 __attribute__((ext_vector_type(4)));
typedef short bf16x8 __attribute__((ext_vector_type(8)));
typedef short bf16x4 __attribute__((ext_vector_type(4)));
typedef unsigned u32x4 __attribute__((ext_vector_type(4)));

#define DI __device__ __forceinline__

constexpr int B_ = 4, S_ = 2048, E_ = 1024, H_ = 16, D_ = 64;
constexpr int M_ = B_ * S_;
constexpr float QSCALE = 0.03125f * 1.4426950408889634f;  // 1/sqrt(E) * log2(e)

DI unsigned short bfbits(float f) {
  __hip_bfloat16 h = __float2bfloat16(f);
  return *reinterpret_cast<unsigned short*>(&h);
}

DI unsigned cvt_pk_bf16(float lo, float hi) {
  unsigned r;
  asm("v_cvt_pk_bf16_f32 %0, %1, %2" : "=v"(r) : "v"(lo), "v"(hi));
  return r;
}

DI void gload_lds16(const bf16* g, bf16* l) {
  __builtin_amdgcn_global_load_lds((const __attribute__((address_space(1))) void*)g,
                                   (__attribute__((address_space(3))) void*)l, 16, 0, 0);
}

// ---------------- fused cast f32->bf16 (x + 3 weights) ----------------
__global__ __launch_bounds__(256) void cast_all(const float* __restrict__ x,
                                                const float* __restrict__ wq,
                                                const float* __restrict__ wk,
                                                const float* __restrict__ wv,
                                                ushort* __restrict__ xb,
                                                ushort* __restrict__ wqb,
                                                ushort* __restrict__ wkb,
                                                ushort* __restrict__ wvb) {
  int id = blockIdx.x * 256 + threadIdx.x;
  const float* src; ushort* dst; int i;
  if (id < 2097152)      { src = x;  dst = xb;  i = id; }
  else if (id < 2359296) { src = wq; dst = wqb; i = id - 2097152; }
  else if (id < 2621440) { src = wk; dst = wkb; i = id - 2359296; }
  else                   { src = wv; dst = wvb; i = id - 2621440; }
  float4 v = reinterpret_cast<const float4*>(src)[i];
  ushort4 o;
  o.x = bfbits(v.x); o.y = bfbits(v.y); o.z = bfbits(v.z); o.w = bfbits(v.w);
  reinterpret_cast<ushort4*>(dst)[i] = o;
}

// ---------------- fused QKV projection GEMM ----------------
// C = A @ W^T for W in {Wq,Wk,Wv}; 1536 blocks, XCD-major over m so each
// XCD's L2 holds its 2MB A slice (A fetched from HBM once, not 8x).
__global__ __launch_bounds__(256) void gemm_qkv_fused(const bf16* __restrict__ A,
                                                      const bf16* __restrict__ Wq,
                                                      const bf16* __restrict__ Wk,
                                                      const bf16* __restrict__ Wv,
                                                      bf16* __restrict__ Qh,
                                                      bf16* __restrict__ Kh,
                                                      bf16* __restrict__ Vth) {
  constexpr int BM = 128, BN = 128, BK = 32, NK = E_ / BK;
  __shared__ __align__(16) bf16 As[2][BM * BK];
  __shared__ __align__(16) bf16 Bs[2][BN * BK];
  const int t = threadIdx.x, l = t & 63, w = t >> 6;
  const int wm = w >> 1, wn = w & 1;

  const int bid = blockIdx.x;
  const int xcd = bid & 7, jq = bid >> 3;
  const int m0 = (xcd * 8 + (jq & 7)) * BM;   // XCD x owns m-tiles [8x,8x+8)
  const int ntile = jq >> 3;                   // 0..23 over N=3072
  const int sec = ntile >> 3;                  // 0:Q 1:K 2:V
  const int n0 = (ntile & 7) * BN;
  const bf16* W = sec == 0 ? Wq : (sec == 1 ? Wk : Wv);

  f32x4 acc[4][4] = {};

  auto stage = [&](int buf, int kt) {
#pragma unroll
    for (int i = 0; i < 2; ++i) {
      int t2 = i * 256 + t;
      int r = t2 >> 2, sl = t2 & 3;
      int g = sl ^ ((r >> 1) & 3);
      gload_lds16(A + (size_t)(m0 + r) * E_ + kt * BK + g * 8,
                  &As[buf][(size_t)(i * 256 + w * 64) * 8]);
      gload_lds16(W + (size_t)(n0 + r) * E_ + kt * BK + g * 8,
                  &Bs[buf][(size_t)(i * 256 + w * 64) * 8]);
    }
  };

  auto tile = [&](int buf) {
    bf16x8 af[4], bfr[4];
#pragma unroll
    for (int i = 0; i < 4; ++i) {
      int ra = wm * 64 + i * 16 + (l & 15);
      int sla = (l >> 4) ^ ((ra >> 1) & 3);
      af[i] = *reinterpret_cast<const bf16x8*>(&As[buf][(ra * 4 + sla) * 8]);
      int rb = wn * 64 + i * 16 + (l & 15);
      int slb = (l >> 4) ^ ((rb >> 1) & 3);
      bfr[i] = *reinterpret_cast<const bf16x8*>(&Bs[buf][(rb * 4 + slb) * 8]);
    }
#pragma unroll
    for (int i = 0; i < 4; ++i)
#pragma unroll
      for (int j = 0; j < 4; ++j)
        acc[i][j] = __builtin_amdgcn_mfma_f32_16x16x32_bf16(af[i], bfr[j], acc[i][j], 0, 0, 0);
  };

  stage(0, 0);
  for (int kt = 0; kt < NK; kt += 2) {
    __syncthreads();
    if (kt + 1 < NK) stage(1, kt + 1);
    tile(0);
    __syncthreads();
    if (kt + 2 < NK) stage(0, kt + 2);
    tile(1);
  }

  const float oscale = (sec == 0) ? QSCALE : 1.0f;
  bf16* dst = sec == 0 ? Qh : (sec == 1 ? Kh : Vth);
#pragma unroll
  for (int i = 0; i < 4; ++i)
#pragma unroll
    for (int j = 0; j < 4; ++j)
#pragma unroll
      for (int jj = 0; jj < 4; ++jj) {
        int mr = m0 + wm * 64 + i * 16 + (l >> 4) * 4 + jj;
        int nc = n0 + wn * 64 + j * 16 + (l & 15);
        int b = mr >> 11, s = mr & 2047, h = nc >> 6, d = nc & 63;
        size_t idx;
        if (sec == 2) idx = ((size_t)(b * H_ + h) * D_ + d) * S_ + s;  // V^T [B,H,D,S]
        else          idx = ((size_t)(b * H_ + h) * S_ + s) * D_ + d;  // [B,H,S,D]
        dst[idx] = __float2bfloat16(acc[i][j][jj] * oscale);
      }
}

// ---------------- flash attention: swapped QK^T, in-register P ----------------
// sc = mfma(K,Q) -> D[kv][q]: lane holds q-col (l&15), kv rows nt*16+4*hi+jj.
// PV uses a k-slot permutation sigma(8hi+j) = 32c+4hi+(j<4?j:16+j-4) applied
// identically to P (packed in-register) and V (two b64 reads per fragment).
__global__ __launch_bounds__(256) void attn_kernel(const bf16* __restrict__ Q,
                                                   const bf16* __restrict__ K,
                                                   const bf16* __restrict__ Vt,
                                                   float* __restrict__ out) {
  constexpr int KT = 64, NT = S_ / KT;
  __shared__ __align__(16) bf16 Ks[2][KT * D_];   // [kv][d], 8-col blocks XOR (kv&7)
  __shared__ __align__(16) bf16 Vs[2][D_ * KT];   // [d][kv], 8-col blocks XOR (d&7)

  const int t = threadIdx.x, l = t & 63, w = t >> 6;
  const int hi = l >> 4, r15 = l & 15;
  const int p = blockIdx.x;
  const int lg = (p & 7) * 256 + (p >> 3);        // XCD-chunked (2048 = 8*256)
  const int qblk = lg & 31, h = (lg >> 5) & 15, b = lg >> 9;
  const int q0 = qblk * 64 + w * 16;
  const size_t bh = (size_t)(b * H_ + h);
  const bf16* Qb = Q + bh * S_ * D_;
  const bf16* Kb = K + bh * S_ * D_;
  const bf16* Vb = Vt + bh * D_ * S_;

  // Q fragments (pre-scaled by QSCALE*log2e at GEMM epilogue)
  bf16x8 aq[2];
#pragma unroll
  for (int c = 0; c < 2; ++c)
    aq[c] = *reinterpret_cast<const bf16x8*>(Qb + (size_t)(q0 + r15) * D_ + c * 32 + hi * 8);

  // precomputed LDS byte offsets (loop-invariant)
  int koff[2][4], voff[2][4][2];
#pragma unroll
  for (int c = 0; c < 2; ++c)
#pragma unroll
    for (int nt = 0; nt < 4; ++nt) {
      int r = nt * 16 + r15;
      koff[c][nt] = (r * D_ + ((4 * c + hi) ^ (r & 7)) * 8) * 2;
      int d = nt * 16 + r15;
#pragma unroll
      for (int hf = 0; hf < 2; ++hf) {
        int blk = 4 * c + 2 * hf + (hi >> 1);     // kv block of 8
        voff[c][nt][hf] = (d * KT + ((blk ^ (d & 7)) * 8) + 4 * (hi & 1)) * 2;
      }
    }

  f32x4 o_acc[4] = {};
  float lsum = 0.f;

  auto stage = [&](int buf, int kt) {
    const bf16* Kt_ = Kb + (size_t)kt * KT * D_;
    const bf16* Vt_ = Vb + kt * KT;
#pragma unroll
    for (int i = 0; i < 2; ++i) {
      int idx = i * 256 + t;
      int rr = idx >> 3, s = idx & 7;
      int g = s ^ (rr & 7);  // inverse-swizzled source, linear LDS dest
      gload_lds16(Kt_ + rr * D_ + g * 8, &Ks[buf][(i * 256 + w * 64) * 8]);
      gload_lds16(Vt_ + (size_t)rr * S_ + g * 8, &Vs[buf][(i * 256 + w * 64) * 8]);
    }
  };

  auto tile = [&](int buf) {
    const char* kbase = (const char*)Ks[buf];
    const char* vbase = (const char*)Vs[buf];
    // swapped QK^T
    f32x4 sc[4] = {};
#pragma unroll
    for (int c = 0; c < 2; ++c)
#pragma unroll
      for (int nt = 0; nt < 4; ++nt) {
        bf16x8 bk = *reinterpret_cast<const bf16x8*>(kbase + koff[c][nt]);
        sc[nt] = __builtin_amdgcn_mfma_f32_16x16x32_bf16(bk, aq[c], sc[nt], 0, 0, 0);
      }
    // softmax (fixed-max: p = 2^s) + pack P into PV A-fragments in-register
    u32x4 pa[2];
#pragma unroll
    for (int nt = 0; nt < 4; ++nt) {
      float pf0 = __builtin_amdgcn_exp2f(sc[nt][0]);
      float pf1 = __builtin_amdgcn_exp2f(sc[nt][1]);
      float pf2 = __builtin_amdgcn_exp2f(sc[nt][2]);
      float pf3 = __builtin_amdgcn_exp2f(sc[nt][3]);
      lsum += (pf0 + pf1) + (pf2 + pf3);
      pa[nt >> 1][(nt & 1) * 2 + 0] = cvt_pk_bf16(pf0, pf1);
      pa[nt >> 1][(nt & 1) * 2 + 1] = cvt_pk_bf16(pf2, pf3);
    }
    // PV with permuted k-slots
#pragma unroll
    for (int c = 0; c < 2; ++c) {
      bf16x8 ap = __builtin_bit_cast(bf16x8, pa[c]);
#pragma unroll
      for (int nt = 0; nt < 4; ++nt) {
        bf16x4 v0 = *reinterpret_cast<const bf16x4*>(vbase + voff[c][nt][0]);
        bf16x4 v1 = *reinterpret_cast<const bf16x4*>(vbase + voff[c][nt][1]);
        bf16x8 bv;
#pragma unroll
        for (int e = 0; e < 4; ++e) { bv[e] = v0[e]; bv[e + 4] = v1[e]; }
        o_acc[nt] = __builtin_amdgcn_mfma_f32_16x16x32_bf16(ap, bv, o_acc[nt], 0, 0, 0);
      }
    }
  };

  stage(0, 0);
  for (int kt = 0; kt < NT; kt += 2) {
    __syncthreads();
    if (kt + 1 < NT) stage(1, kt + 1);
    tile(0);
    __syncthreads();
    if (kt + 2 < NT) stage(0, kt + 2);
    tile(1);
  }

  // row sums: lane's lsum covers its q=r15, kv slots of its hi-group
  lsum += __shfl_xor(lsum, 16);
  lsum += __shfl_xor(lsum, 32);
  float inv = 1.f / lsum;
  // redistribute: o_acc rows are q = 4*hi+jj, inv lives at lane r15==q
#pragma unroll
  for (int jj = 0; jj < 4; ++jj) {
    float invj = __shfl(inv, (l & 48) + hi * 4 + jj);
    int q = q0 + hi * 4 + jj;
#pragma unroll
    for (int nt = 0; nt < 4; ++nt) {
      int d = nt * 16 + r15;
      out[((size_t)b * S_ + q) * E_ + h * D_ + d] = o_acc[nt][jj] * invj;
    }
  }
}

extern "C" void kernel_launch(void* const* d_in, const int* in_sizes, int n_in,
                              void* d_out, int out_size, void* d_ws, size_t ws_size,
                              hipStream_t stream) {
  const float* x = (const float*)d_in[0];
  const float* wq = (const float*)d_in[1];
  const float* wk = (const float*)d_in[2];
  const float* wv = (const float*)d_in[3];
  float* out = (float*)d_out;
  char* ws = (char*)d_ws;

  bf16* xb  = (bf16*)(ws + 0);          // 16 MiB [8192][1024]
  bf16* wqb = (bf16*)(ws + 16777216);   // 2 MiB
  bf16* wkb = (bf16*)(ws + 18874368);   // 2 MiB
  bf16* wvb = (bf16*)(ws + 20971520);   // 2 MiB
  bf16* Qh  = (bf16*)(ws + 23068672);   // 16 MiB [B,H,S,D] (pre-scaled)
  bf16* Kh  = (bf16*)(ws + 39845888);   // 16 MiB [B,H,S,D]
  bf16* Vth = (bf16*)(ws + 56623104);   // 16 MiB [B,H,D,S]

  cast_all<<<11264, 256, 0, stream>>>(x, wq, wk, wv, (ushort*)xb, (ushort*)wqb,
                                      (ushort*)wkb, (ushort*)wvb);

  gemm_qkv_fused<<<1536, 256, 0, stream>>>(xb, wqb, wkb, wvb, Qh, Kh, Vth);

  attn_kernel<<<2048, 256, 0, stream>>>(Qh, Kh, Vth, out);
}

// Round 5
// 265.333 us; speedup vs baseline: 1.5149x; 1.0505x over previous
//
#include <hip/hip_runtime.h>
#include <hip/hip_bf16.h>

typedef __hip_bfloat16 bf16;
typedef float f32x4 __attribute__((ext_vector_type(4)));
typedef short bf16x8 __attribute__((ext_vector_type(8)));
typedef short bf16x4 __attribute__((ext_vector_type(4)));
typedef unsigned u32x4 __attribute__((ext_vector_type(4)));

#define DI __device__ __forceinline__

constexpr int B_ = 4, S_ = 2048, E_ = 1024, H_ = 16, D_ = 64;
constexpr int M_ = B_ * S_;
constexpr float QSCALE = 0.03125f * 1.4426950408889634f;  // 1/sqrt(E) * log2(e)

DI unsigned short bfbits(float f) {
  __hip_bfloat16 h = __float2bfloat16(f);
  return *reinterpret_cast<unsigned short*>(&h);
}

DI unsigned cvt_pk_bf16(float lo, float hi) {
  unsigned r;
  asm("v_cvt_pk_bf16_f32 %0, %1, %2" : "=v"(r) : "v"(lo), "v"(hi));
  return r;
}

DI void gload_lds16(const bf16* g, bf16* l) {
  __builtin_amdgcn_global_load_lds((const __attribute__((address_space(1))) void*)g,
                                   (__attribute__((address_space(3))) void*)l, 16, 0, 0);
}

// ---------------- fused cast f32->bf16 (x + 3 weights) ----------------
__global__ __launch_bounds__(256) void cast_all(const float* __restrict__ x,
                                                const float* __restrict__ wq,
                                                const float* __restrict__ wk,
                                                const float* __restrict__ wv,
                                                ushort* __restrict__ xb,
                                                ushort* __restrict__ wqb,
                                                ushort* __restrict__ wkb,
                                                ushort* __restrict__ wvb) {
  int id = blockIdx.x * 256 + threadIdx.x;
  const float* src; ushort* dst; int i;
  if (id < 2097152)      { src = x;  dst = xb;  i = id; }
  else if (id < 2359296) { src = wq; dst = wqb; i = id - 2097152; }
  else if (id < 2621440) { src = wk; dst = wkb; i = id - 2359296; }
  else                   { src = wv; dst = wvb; i = id - 2621440; }
  float4 v = reinterpret_cast<const float4*>(src)[i];
  ushort4 o;
  o.x = bfbits(v.x); o.y = bfbits(v.y); o.z = bfbits(v.z); o.w = bfbits(v.w);
  reinterpret_cast<ushort4*>(dst)[i] = o;
}

// ---------------- fused QKV projection: 256x256 tile, 8-phase counted-vmcnt ----
// C[8192][3072] = A @ [Wq;Wk;Wv]^T. W rows 0..3071 contiguous (wqb,wkb,wvb
// adjacent in ws). Ring of 4 LDS slots (32KB: A 256x32 + B 256x32 bf16),
// granule = K-slice of 32. Granule g computes slot g&3 while staging g+2.
// vmcnt(4) at granule end => next granule landed, 4 loads stay in flight.
__global__ __launch_bounds__(512, 2) void gemm_qkv_8ph(const bf16* __restrict__ A,
                                                       const bf16* __restrict__ W,
                                                       bf16* __restrict__ Qh,
                                                       bf16* __restrict__ Kh,
                                                       bf16* __restrict__ Vth) {
  constexpr int NG = E_ / 32;                    // 32 granules
  __shared__ __align__(16) bf16 lds[65536];      // 128 KiB: 4 slots x 16384 elems
  const int t = threadIdx.x, l = t & 63, w = t >> 6;
  const int hi = l >> 4, r15 = l & 15;
  const int wm = w >> 2, wn = w & 3;             // wave grid 2x4

  const int bid = blockIdx.x;
  const int swz = (bid & 7) * 48 + (bid >> 3);   // XCD-chunked, 384 = 8*48
  const int mt = swz / 12, nt = swz - mt * 12;
  const int m0 = mt * 256, n0 = nt * 256;

  f32x4 acc[8][4] = {};

  // stage one matrix (kind 0=A,1=B) of granule g into its ring slot.
  auto stageM = [&](int g, int kind) {
    const bf16* src = (kind == 0) ? A + (size_t)m0 * E_ : W + (size_t)n0 * E_;
    bf16* base = lds + (size_t)(g & 3) * 16384 + kind * 8192 + (w * 64) * 8;
#pragma unroll
    for (int i2 = 0; i2 < 2; ++i2) {
      int gr = i2 * 512 + t;
      int row = gr >> 2, slot = gr & 3;
      int ch = slot ^ (row & 3);                 // inverse chunk swizzle on source
      gload_lds16(src + (size_t)row * E_ + g * 32 + ch * 8, base + i2 * 4096);
    }
  };

  // prologue: granules 0,1 staged; g0 guaranteed landed, g1 in flight.
  stageM(0, 0); stageM(0, 1);
  stageM(1, 0); stageM(1, 1);
  asm volatile("s_waitcnt vmcnt(4)" ::: "memory");
  __builtin_amdgcn_s_barrier();

  for (int g = 0; g < NG; ++g) {
    const char* sa = (const char*)(lds + (size_t)(g & 3) * 16384);
    const char* sb = sa + 8192 * 2;
    bf16x8 bfrag[4];
#pragma unroll
    for (int mg = 0; mg < 2; ++mg) {
      // ---- phase: read frags ----
      bf16x8 afrag[4];
#pragma unroll
      for (int mm = 0; mm < 4; ++mm) {
        int row = wm * 128 + (mg * 4 + mm) * 16 + r15;
        afrag[mm] = *(const bf16x8*)(sa + row * 64 + ((hi ^ (row & 3)) * 16));
      }
      if (mg == 0) {
#pragma unroll
        for (int nf = 0; nf < 4; ++nf) {
          int row = wn * 64 + nf * 16 + r15;
          bfrag[nf] = *(const bf16x8*)(sb + row * 64 + ((hi ^ (row & 3)) * 16));
        }
      }
      // ---- stage half of granule g+2 ----
      if (g < NG - 2) stageM(g + 2, mg);
      __builtin_amdgcn_s_barrier();
      asm volatile("s_waitcnt lgkmcnt(0)" ::: "memory");
      __builtin_amdgcn_sched_barrier(0);
      __builtin_amdgcn_s_setprio(1);
#pragma unroll
      for (int mm = 0; mm < 4; ++mm)
#pragma unroll
        for (int nf = 0; nf < 4; ++nf)
          acc[mg * 4 + mm][nf] =
              __builtin_amdgcn_mfma_f32_16x16x32_bf16(afrag[mm], bfrag[nf],
                                                      acc[mg * 4 + mm][nf], 0, 0, 0);
      __builtin_amdgcn_s_setprio(0);
      if (mg == 1) {  // granule boundary: counted wait BEFORE the barrier
        if (g < NG - 2)       asm volatile("s_waitcnt vmcnt(4)" ::: "memory");
        else if (g == NG - 2) asm volatile("s_waitcnt vmcnt(0)" ::: "memory");
      }
      __builtin_amdgcn_s_barrier();
    }
  }

  // ---------------- epilogue: per-wave 16KB LDS transpose, coalesced stores ----
  const int ncol0 = n0 + wn * 64;
  const int sec = ncol0 >> 10;                    // 0:Q 1:K 2:V
  const int h = (ncol0 >> 6) & 15;
  const int mrow = m0 + wm * 128;
  const int b = mrow >> 11, sbase = mrow & 2047;
  char* wb = (char*)lds + w * 16384;

  if (sec < 2) {
    bf16* dst = sec == 0 ? Qh : Kh;
    const float osc = sec == 0 ? QSCALE : 1.0f;
    // write [s 128][d 64] bf16, chunk-XOR by s&7
#pragma unroll
    for (int mf = 0; mf < 8; ++mf)
#pragma unroll
      for (int nf = 0; nf < 4; ++nf)
#pragma unroll
        for (int jj = 0; jj < 4; ++jj) {
          int s = mf * 16 + 4 * hi + jj;
          int d = nf * 16 + r15;
          *(bf16*)(wb + s * 128 + ((d * 2) ^ ((s & 7) << 4))) =
              __float2bfloat16(acc[mf][nf][jj] * osc);
        }
    asm volatile("s_waitcnt lgkmcnt(0)" ::: "memory");
    __builtin_amdgcn_sched_barrier(0);
    bf16* obase = dst + ((size_t)(b * H_ + h) * S_ + sbase) * D_;
#pragma unroll
    for (int c = 0; c < 16; ++c) {
      int s = c * 8 + (l >> 3), dch = l & 7;
      bf16x8 v = *(const bf16x8*)(wb + s * 128 + ((dch * 16) ^ ((s & 7) << 4)));
      *(bf16x8*)(obase + (size_t)s * D_ + dch * 8) = v;
    }
  } else {
    // V: write [d 64][s 128] via cvt_pk b32, chunk-XOR by d&7; store V^T rows
#pragma unroll
    for (int mf = 0; mf < 8; ++mf)
#pragma unroll
      for (int nf = 0; nf < 4; ++nf)
#pragma unroll
        for (int m2 = 0; m2 < 2; ++m2) {
          int s = mf * 16 + 4 * hi + m2 * 2;
          int d = nf * 16 + r15;
          unsigned u = cvt_pk_bf16(acc[mf][nf][m2 * 2], acc[mf][nf][m2 * 2 + 1]);
          *(unsigned*)(wb + d * 256 + ((s * 2) ^ ((d & 7) << 4))) = u;
        }
    asm volatile("s_waitcnt lgkmcnt(0)" ::: "memory");
    __builtin_amdgcn_sched_barrier(0);
    const int d = l;                               // wave's 64 d-rows
    bf16* obase = Vth + ((size_t)(b * H_ + h) * D_ + d) * S_ + sbase;
#pragma unroll
    for (int c = 0; c < 16; ++c) {
      bf16x8 v = *(const bf16x8*)(wb + d * 256 + ((c * 16) ^ ((d & 7) << 4)));
      *(bf16x8*)(obase + c * 8) = v;
    }
  }
}

// ---------------- flash attention: swapped QK^T, in-register P (unchanged R3) --
__global__ __launch_bounds__(256) void attn_kernel(const bf16* __restrict__ Q,
                                                   const bf16* __restrict__ K,
                                                   const bf16* __restrict__ Vt,
                                                   float* __restrict__ out) {
  constexpr int KT = 64, NT = S_ / KT;
  __shared__ __align__(16) bf16 Ks[2][KT * D_];
  __shared__ __align__(16) bf16 Vs[2][D_ * KT];

  const int t = threadIdx.x, l = t & 63, w = t >> 6;
  const int hi = l >> 4, r15 = l & 15;
  const int p = blockIdx.x;
  const int lg = (p & 7) * 256 + (p >> 3);
  const int qblk = lg & 31, h = (lg >> 5) & 15, b = lg >> 9;
  const int q0 = qblk * 64 + w * 16;
  const size_t bh = (size_t)(b * H_ + h);
  const bf16* Qb = Q + bh * S_ * D_;
  const bf16* Kb = K + bh * S_ * D_;
  const bf16* Vb = Vt + bh * D_ * S_;

  bf16x8 aq[2];
#pragma unroll
  for (int c = 0; c < 2; ++c)
    aq[c] = *reinterpret_cast<const bf16x8*>(Qb + (size_t)(q0 + r15) * D_ + c * 32 + hi * 8);

  int koff[2][4], voff[2][4][2];
#pragma unroll
  for (int c = 0; c < 2; ++c)
#pragma unroll
    for (int nt = 0; nt < 4; ++nt) {
      int r = nt * 16 + r15;
      koff[c][nt] = (r * D_ + ((4 * c + hi) ^ (r & 7)) * 8) * 2;
      int d = nt * 16 + r15;
#pragma unroll
      for (int hf = 0; hf < 2; ++hf) {
        int blk = 4 * c + 2 * hf + (hi >> 1);
        voff[c][nt][hf] = (d * KT + ((blk ^ (d & 7)) * 8) + 4 * (hi & 1)) * 2;
      }
    }

  f32x4 o_acc[4] = {};
  float lsum = 0.f;

  auto stage = [&](int buf, int kt) {
    const bf16* Kt_ = Kb + (size_t)kt * KT * D_;
    const bf16* Vt_ = Vb + kt * KT;
#pragma unroll
    for (int i = 0; i < 2; ++i) {
      int idx = i * 256 + t;
      int rr = idx >> 3, s = idx & 7;
      int g = s ^ (rr & 7);
      gload_lds16(Kt_ + rr * D_ + g * 8, &Ks[buf][(i * 256 + w * 64) * 8]);
      gload_lds16(Vt_ + (size_t)rr * S_ + g * 8, &Vs[buf][(i * 256 + w * 64) * 8]);
    }
  };

  auto tile = [&](int buf) {
    const char* kbase = (const char*)Ks[buf];
    const char* vbase = (const char*)Vs[buf];
    f32x4 sc[4] = {};
#pragma unroll
    for (int c = 0; c < 2; ++c)
#pragma unroll
      for (int nt = 0; nt < 4; ++nt) {
        bf16x8 bk = *reinterpret_cast<const bf16x8*>(kbase + koff[c][nt]);
        sc[nt] = __builtin_amdgcn_mfma_f32_16x16x32_bf16(bk, aq[c], sc[nt], 0, 0, 0);
      }
    u32x4 pa[2];
#pragma unroll
    for (int nt = 0; nt < 4; ++nt) {
      float pf0 = __builtin_amdgcn_exp2f(sc[nt][0]);
      float pf1 = __builtin_amdgcn_exp2f(sc[nt][1]);
      float pf2 = __builtin_amdgcn_exp2f(sc[nt][2]);
      float pf3 = __builtin_amdgcn_exp2f(sc[nt][3]);
      lsum += (pf0 + pf1) + (pf2 + pf3);
      pa[nt >> 1][(nt & 1) * 2 + 0] = cvt_pk_bf16(pf0, pf1);
      pa[nt >> 1][(nt & 1) * 2 + 1] = cvt_pk_bf16(pf2, pf3);
    }
#pragma unroll
    for (int c = 0; c < 2; ++c) {
      bf16x8 ap = __builtin_bit_cast(bf16x8, pa[c]);
#pragma unroll
      for (int nt = 0; nt < 4; ++nt) {
        bf16x4 v0 = *reinterpret_cast<const bf16x4*>(vbase + voff[c][nt][0]);
        bf16x4 v1 = *reinterpret_cast<const bf16x4*>(vbase + voff[c][nt][1]);
        bf16x8 bv;
#pragma unroll
        for (int e = 0; e < 4; ++e) { bv[e] = v0[e]; bv[e + 4] = v1[e]; }
        o_acc[nt] = __builtin_amdgcn_mfma_f32_16x16x32_bf16(ap, bv, o_acc[nt], 0, 0, 0);
      }
    }
  };

  stage(0, 0);
  for (int kt = 0; kt < NT; kt += 2) {
    __syncthreads();
    if (kt + 1 < NT) stage(1, kt + 1);
    tile(0);
    __syncthreads();
    if (kt + 2 < NT) stage(0, kt + 2);
    tile(1);
  }

  lsum += __shfl_xor(lsum, 16);
  lsum += __shfl_xor(lsum, 32);
  float inv = 1.f / lsum;
#pragma unroll
  for (int jj = 0; jj < 4; ++jj) {
    float invj = __shfl(inv, (l & 48) + hi * 4 + jj);
    int q = q0 + hi * 4 + jj;
#pragma unroll
    for (int nt = 0; nt < 4; ++nt) {
      int d = nt * 16 + r15;
      out[((size_t)b * S_ + q) * E_ + h * D_ + d] = o_acc[nt][jj] * invj;
    }
  }
}

extern "C" void kernel_launch(void* const* d_in, const int* in_sizes, int n_in,
                              void* d_out, int out_size, void* d_ws, size_t ws_size,
                              hipStream_t stream) {
  const float* x = (const float*)d_in[0];
  const float* wq = (const float*)d_in[1];
  const float* wk = (const float*)d_in[2];
  const float* wv = (const float*)d_in[3];
  float* out = (float*)d_out;
  char* ws = (char*)d_ws;

  // workspace layout; wqb/wkb/wvb are contiguous = W_all [3072][1024]
  bf16* xb  = (bf16*)(ws + 0);          // 16 MiB [8192][1024]
  bf16* wqb = (bf16*)(ws + 16777216);   // 2 MiB
  bf16* wkb = (bf16*)(ws + 18874368);   // 2 MiB
  bf16* wvb = (bf16*)(ws + 20971520);   // 2 MiB
  bf16* Qh  = (bf16*)(ws + 23068672);   // 16 MiB [B,H,S,D] (pre-scaled)
  bf16* Kh  = (bf16*)(ws + 39845888);   // 16 MiB [B,H,S,D]
  bf16* Vth = (bf16*)(ws + 56623104);   // 16 MiB [B,H,D,S]

  cast_all<<<11264, 256, 0, stream>>>(x, wq, wk, wv, (ushort*)xb, (ushort*)wqb,
                                      (ushort*)wkb, (ushort*)wvb);

  gemm_qkv_8ph<<<384, 512, 0, stream>>>(xb, wqb, Qh, Kh, Vth);

  attn_kernel<<<2048, 256, 0, stream>>>(Qh, Kh, Vth, out);
}

// Round 6
// 245.312 us; speedup vs baseline: 1.6386x; 1.0816x over previous
//
#include <hip/hip_runtime.h>
#include <hip/hip_bf16.h>

typedef __hip_bfloat16 bf16;
typedef float f32x4 __attribute__((ext_vector_type(4)));
typedef short bf16x8 __attribute__((ext_vector_type(8)));
typedef short bf16x4 __attribute__((ext_vector_type(4)));
typedef unsigned u32x4 __attribute__((ext_vector_type(4)));

#define DI __device__ __forceinline__

constexpr int B_ = 4, S_ = 2048, E_ = 1024, H_ = 16, D_ = 64;
constexpr int M_ = B_ * S_;
constexpr float QSCALE = 0.03125f * 1.4426950408889634f;  // 1/sqrt(E) * log2(e)

DI unsigned short bfbits(float f) {
  __hip_bfloat16 h = __float2bfloat16(f);
  return *reinterpret_cast<unsigned short*>(&h);
}

DI unsigned cvt_pk_bf16(float lo, float hi) {
  unsigned r;
  asm("v_cvt_pk_bf16_f32 %0, %1, %2" : "=v"(r) : "v"(lo), "v"(hi));
  return r;
}

DI void gload_lds16(const bf16* g, bf16* l) {
  __builtin_amdgcn_global_load_lds((const __attribute__((address_space(1))) void*)g,
                                   (__attribute__((address_space(3))) void*)l, 16, 0, 0);
}

// ---------------- fused cast f32->bf16 (x + 3 weights) ----------------
__global__ __launch_bounds__(256) void cast_all(const float* __restrict__ x,
                                                const float* __restrict__ wq,
                                                const float* __restrict__ wk,
                                                const float* __restrict__ wv,
                                                ushort* __restrict__ xb,
                                                ushort* __restrict__ wqb,
                                                ushort* __restrict__ wkb,
                                                ushort* __restrict__ wvb) {
  int id = blockIdx.x * 256 + threadIdx.x;
  const float* src; ushort* dst; int i;
  if (id < 2097152)      { src = x;  dst = xb;  i = id; }
  else if (id < 2359296) { src = wq; dst = wqb; i = id - 2097152; }
  else if (id < 2621440) { src = wk; dst = wkb; i = id - 2359296; }
  else                   { src = wv; dst = wvb; i = id - 2621440; }
  float4 v = reinterpret_cast<const float4*>(src)[i];
  ushort4 o;
  o.x = bfbits(v.x); o.y = bfbits(v.y); o.z = bfbits(v.z); o.w = bfbits(v.w);
  reinterpret_cast<ushort4*>(dst)[i] = o;
}

// ---------------- fused QKV projection: 256x256 tile, 8-phase counted-vmcnt ----
// Ring of 4 LDS slots; granule = K-slice of 32. Prefetch depth 3 granules:
// during granule g stage g+3; vmcnt(8) at granule end (leaves g+2,g+3 in
// flight, guarantees g+1 landed). Swizzle: chunk XOR (row>>1)&3 (2-way free).
__global__ __launch_bounds__(512, 2) void gemm_qkv_8ph(const bf16* __restrict__ A,
                                                       const bf16* __restrict__ W,
                                                       bf16* __restrict__ Qh,
                                                       bf16* __restrict__ Kh,
                                                       bf16* __restrict__ Vth) {
  constexpr int NG = E_ / 32;                    // 32 granules
  __shared__ __align__(16) bf16 lds[65536];      // 128 KiB: 4 slots x 16384 elems
  const int t = threadIdx.x, l = t & 63, w = t >> 6;
  const int hi = l >> 4, r15 = l & 15;
  const int wm = w >> 2, wn = w & 3;             // wave grid 2x4

  // XCD 2D patches: xcd covers 8 m-tiles x 6 n-tiles (A 4MB + B 3MB in L2)
  const int bid = blockIdx.x;
  const int xcd = bid & 7, j = bid >> 3;         // j in 0..47
  const int mt = (xcd >> 1) * 8 + (j & 7);
  const int nt = (xcd & 1) * 6 + (j >> 3);
  const int m0 = mt * 256, n0 = nt * 256;

  f32x4 acc[8][4] = {};

  auto stageM = [&](int g, int kind) {
    const bf16* src = (kind == 0) ? A + (size_t)m0 * E_ : W + (size_t)n0 * E_;
    bf16* base = lds + (size_t)(g & 3) * 16384 + kind * 8192 + (w * 64) * 8;
#pragma unroll
    for (int i2 = 0; i2 < 2; ++i2) {
      int gr = i2 * 512 + t;
      int row = gr >> 2, slot = gr & 3;
      int ch = slot ^ ((row >> 1) & 3);          // inverse chunk swizzle on source
      gload_lds16(src + (size_t)row * E_ + g * 32 + ch * 8, base + i2 * 4096);
    }
  };

  // prologue: stage granules 0,1,2 (12 loads); wait g0 landed.
  stageM(0, 0); stageM(0, 1);
  stageM(1, 0); stageM(1, 1);
  stageM(2, 0); stageM(2, 1);
  asm volatile("s_waitcnt vmcnt(8)" ::: "memory");
  __builtin_amdgcn_s_barrier();

  for (int g = 0; g < NG; ++g) {
    const char* sa = (const char*)(lds + (size_t)(g & 3) * 16384);
    const char* sb = sa + 8192 * 2;
    bf16x8 bfrag[4];
#pragma unroll
    for (int mg = 0; mg < 2; ++mg) {
      bf16x8 afrag[4];
#pragma unroll
      for (int mm = 0; mm < 4; ++mm) {
        int row = wm * 128 + (mg * 4 + mm) * 16 + r15;
        afrag[mm] = *(const bf16x8*)(sa + row * 64 + ((hi ^ ((row >> 1) & 3)) * 16));
      }
      if (mg == 0) {
#pragma unroll
        for (int nf = 0; nf < 4; ++nf) {
          int row = wn * 64 + nf * 16 + r15;
          bfrag[nf] = *(const bf16x8*)(sb + row * 64 + ((hi ^ ((row >> 1) & 3)) * 16));
        }
      }
      if (g < NG - 3) stageM(g + 3, mg);
      __builtin_amdgcn_s_barrier();
      asm volatile("s_waitcnt lgkmcnt(0)" ::: "memory");
      __builtin_amdgcn_sched_barrier(0);
      __builtin_amdgcn_s_setprio(1);
#pragma unroll
      for (int mm = 0; mm < 4; ++mm)
#pragma unroll
        for (int nf = 0; nf < 4; ++nf)
          acc[mg * 4 + mm][nf] =
              __builtin_amdgcn_mfma_f32_16x16x32_bf16(afrag[mm], bfrag[nf],
                                                      acc[mg * 4 + mm][nf], 0, 0, 0);
      __builtin_amdgcn_s_setprio(0);
      if (mg == 1) {  // granule boundary: counted wait BEFORE the barrier
        if (g < NG - 3)       asm volatile("s_waitcnt vmcnt(8)" ::: "memory");
        else if (g == NG - 3) asm volatile("s_waitcnt vmcnt(4)" ::: "memory");
        else if (g == NG - 2) asm volatile("s_waitcnt vmcnt(0)" ::: "memory");
      }
      __builtin_amdgcn_s_barrier();
    }
  }

  // ---------------- epilogue: per-wave 16KB LDS transpose, coalesced stores ----
  const int ncol0 = n0 + wn * 64;
  const int sec = ncol0 >> 10;                    // 0:Q 1:K 2:V
  const int h = (ncol0 >> 6) & 15;
  const int mrow = m0 + wm * 128;
  const int b = mrow >> 11, sbase = mrow & 2047;
  char* wb = (char*)lds + w * 16384;

  if (sec < 2) {
    bf16* dst = sec == 0 ? Qh : Kh;
    const float osc = sec == 0 ? QSCALE : 1.0f;
#pragma unroll
    for (int mf = 0; mf < 8; ++mf)
#pragma unroll
      for (int nf = 0; nf < 4; ++nf)
#pragma unroll
        for (int jj = 0; jj < 4; ++jj) {
          int s = mf * 16 + 4 * hi + jj;
          int d = nf * 16 + r15;
          *(bf16*)(wb + s * 128 + ((d * 2) ^ ((s & 7) << 4))) =
              __float2bfloat16(acc[mf][nf][jj] * osc);
        }
    asm volatile("s_waitcnt lgkmcnt(0)" ::: "memory");
    __builtin_amdgcn_sched_barrier(0);
    bf16* obase = dst + ((size_t)(b * H_ + h) * S_ + sbase) * D_;
#pragma unroll
    for (int c = 0; c < 16; ++c) {
      int s = c * 8 + (l >> 3), dch = l & 7;
      bf16x8 v = *(const bf16x8*)(wb + s * 128 + ((dch * 16) ^ ((s & 7) << 4)));
      *(bf16x8*)(obase + (size_t)s * D_ + dch * 8) = v;
    }
  } else {
#pragma unroll
    for (int mf = 0; mf < 8; ++mf)
#pragma unroll
      for (int nf = 0; nf < 4; ++nf)
#pragma unroll
        for (int m2 = 0; m2 < 2; ++m2) {
          int s = mf * 16 + 4 * hi + m2 * 2;
          int d = nf * 16 + r15;
          unsigned u = cvt_pk_bf16(acc[mf][nf][m2 * 2], acc[mf][nf][m2 * 2 + 1]);
          *(unsigned*)(wb + d * 256 + ((s * 2) ^ ((d & 7) << 4))) = u;
        }
    asm volatile("s_waitcnt lgkmcnt(0)" ::: "memory");
    __builtin_amdgcn_sched_barrier(0);
    const int d = l;
    bf16* obase = Vth + ((size_t)(b * H_ + h) * D_ + d) * S_ + sbase;
#pragma unroll
    for (int c = 0; c < 16; ++c) {
      bf16x8 v = *(const bf16x8*)(wb + d * 256 + ((c * 16) ^ ((d & 7) << 4)));
      *(bf16x8*)(obase + c * 8) = v;
    }
  }
}

// ---------------- flash attention: q-tile 128, swapped QK^T, in-register P ----
// 256 thr = 4 waves; wave owns 32 q rows as 2 row-groups of 16. K-frags and
// V-frags read from LDS once, used by both row-groups (2 MFMA per frag read).
__global__ __launch_bounds__(256) void attn_kernel(const bf16* __restrict__ Q,
                                                   const bf16* __restrict__ K,
                                                   const bf16* __restrict__ Vt,
                                                   float* __restrict__ out) {
  constexpr int KT = 64, NT = S_ / KT;
  __shared__ __align__(16) bf16 Ks[2][KT * D_];
  __shared__ __align__(16) bf16 Vs[2][D_ * KT];

  const int t = threadIdx.x, l = t & 63, w = t >> 6;
  const int hi = l >> 4, r15 = l & 15;
  const int p = blockIdx.x;
  const int lg = (p & 7) * 128 + (p >> 3);        // XCD-chunked (1024 = 8*128)
  const int qblk = lg & 15, h = (lg >> 4) & 15, b = lg >> 8;
  const int q0 = qblk * 128 + w * 32;
  const size_t bh = (size_t)(b * H_ + h);
  const bf16* Qb = Q + bh * S_ * D_;
  const bf16* Kb = K + bh * S_ * D_;
  const bf16* Vb = Vt + bh * D_ * S_;

  // Q fragments (pre-scaled by QSCALE*log2e at GEMM epilogue)
  bf16x8 aq0[2], aq1[2];
#pragma unroll
  for (int c = 0; c < 2; ++c) {
    aq0[c] = *reinterpret_cast<const bf16x8*>(Qb + (size_t)(q0 + r15) * D_ + c * 32 + hi * 8);
    aq1[c] = *reinterpret_cast<const bf16x8*>(Qb + (size_t)(q0 + 16 + r15) * D_ + c * 32 + hi * 8);
  }

  int koff[2][4], voff[2][4][2];
#pragma unroll
  for (int c = 0; c < 2; ++c)
#pragma unroll
    for (int n4 = 0; n4 < 4; ++n4) {
      int r = n4 * 16 + r15;
      koff[c][n4] = (r * D_ + ((4 * c + hi) ^ (r & 7)) * 8) * 2;
      int d = n4 * 16 + r15;
#pragma unroll
      for (int hf = 0; hf < 2; ++hf) {
        int blk = 4 * c + 2 * hf + (hi >> 1);
        voff[c][n4][hf] = (d * KT + ((blk ^ (d & 7)) * 8) + 4 * (hi & 1)) * 2;
      }
    }

  f32x4 o_acc0[4] = {}, o_acc1[4] = {};
  float lsum0 = 0.f, lsum1 = 0.f;

  auto stage = [&](int buf, int kt) {
    const bf16* Kt_ = Kb + (size_t)kt * KT * D_;
    const bf16* Vt_ = Vb + kt * KT;
#pragma unroll
    for (int i = 0; i < 2; ++i) {
      int idx = i * 256 + t;
      int rr = idx >> 3, s = idx & 7;
      int g = s ^ (rr & 7);
      gload_lds16(Kt_ + rr * D_ + g * 8, &Ks[buf][(i * 256 + w * 64) * 8]);
      gload_lds16(Vt_ + (size_t)rr * S_ + g * 8, &Vs[buf][(i * 256 + w * 64) * 8]);
    }
  };

  auto tile = [&](int buf) {
    const char* kbase = (const char*)Ks[buf];
    const char* vbase = (const char*)Vs[buf];
    // swapped QK^T for both row-groups; each K-frag read feeds 2 MFMAs
    f32x4 sc0[4] = {}, sc1[4] = {};
#pragma unroll
    for (int c = 0; c < 2; ++c)
#pragma unroll
      for (int n4 = 0; n4 < 4; ++n4) {
        bf16x8 bk = *reinterpret_cast<const bf16x8*>(kbase + koff[c][n4]);
        sc0[n4] = __builtin_amdgcn_mfma_f32_16x16x32_bf16(bk, aq0[c], sc0[n4], 0, 0, 0);
        sc1[n4] = __builtin_amdgcn_mfma_f32_16x16x32_bf16(bk, aq1[c], sc1[n4], 0, 0, 0);
      }
    // fixed-max softmax + in-register P pack (both row-groups)
    u32x4 pa0[2], pa1[2];
#pragma unroll
    for (int n4 = 0; n4 < 4; ++n4) {
      float a0 = __builtin_amdgcn_exp2f(sc0[n4][0]);
      float a1 = __builtin_amdgcn_exp2f(sc0[n4][1]);
      float a2 = __builtin_amdgcn_exp2f(sc0[n4][2]);
      float a3 = __builtin_amdgcn_exp2f(sc0[n4][3]);
      lsum0 += (a0 + a1) + (a2 + a3);
      pa0[n4 >> 1][(n4 & 1) * 2 + 0] = cvt_pk_bf16(a0, a1);
      pa0[n4 >> 1][(n4 & 1) * 2 + 1] = cvt_pk_bf16(a2, a3);
      float b0 = __builtin_amdgcn_exp2f(sc1[n4][0]);
      float b1 = __builtin_amdgcn_exp2f(sc1[n4][1]);
      float b2 = __builtin_amdgcn_exp2f(sc1[n4][2]);
      float b3 = __builtin_amdgcn_exp2f(sc1[n4][3]);
      lsum1 += (b0 + b1) + (b2 + b3);
      pa1[n4 >> 1][(n4 & 1) * 2 + 0] = cvt_pk_bf16(b0, b1);
      pa1[n4 >> 1][(n4 & 1) * 2 + 1] = cvt_pk_bf16(b2, b3);
    }
    // PV with permuted k-slots; each V-frag read feeds 2 MFMAs
#pragma unroll
    for (int c = 0; c < 2; ++c) {
      bf16x8 ap0 = __builtin_bit_cast(bf16x8, pa0[c]);
      bf16x8 ap1 = __builtin_bit_cast(bf16x8, pa1[c]);
#pragma unroll
      for (int n4 = 0; n4 < 4; ++n4) {
        bf16x4 v0 = *reinterpret_cast<const bf16x4*>(vbase + voff[c][n4][0]);
        bf16x4 v1 = *reinterpret_cast<const bf16x4*>(vbase + voff[c][n4][1]);
        bf16x8 bv;
#pragma unroll
        for (int e = 0; e < 4; ++e) { bv[e] = v0[e]; bv[e + 4] = v1[e]; }
        o_acc0[n4] = __builtin_amdgcn_mfma_f32_16x16x32_bf16(ap0, bv, o_acc0[n4], 0, 0, 0);
        o_acc1[n4] = __builtin_amdgcn_mfma_f32_16x16x32_bf16(ap1, bv, o_acc1[n4], 0, 0, 0);
      }
    }
  };

  stage(0, 0);
  for (int kt = 0; kt < NT; kt += 2) {
    __syncthreads();
    if (kt + 1 < NT) stage(1, kt + 1);
    tile(0);
    __syncthreads();
    if (kt + 2 < NT) stage(0, kt + 2);
    tile(1);
  }

  // row sums (per row-group): lane's lsum covers q=r15 of its group
  lsum0 += __shfl_xor(lsum0, 16);
  lsum0 += __shfl_xor(lsum0, 32);
  lsum1 += __shfl_xor(lsum1, 16);
  lsum1 += __shfl_xor(lsum1, 32);
  float inv0 = 1.f / lsum0, inv1 = 1.f / lsum1;
#pragma unroll
  for (int jj = 0; jj < 4; ++jj) {
    float i0 = __shfl(inv0, (l & 48) + hi * 4 + jj);
    float i1 = __shfl(inv1, (l & 48) + hi * 4 + jj);
    int qa = q0 + hi * 4 + jj;
    int qb2 = q0 + 16 + hi * 4 + jj;
#pragma unroll
    for (int n4 = 0; n4 < 4; ++n4) {
      int d = n4 * 16 + r15;
      out[((size_t)b * S_ + qa) * E_ + h * D_ + d] = o_acc0[n4][jj] * i0;
      out[((size_t)b * S_ + qb2) * E_ + h * D_ + d] = o_acc1[n4][jj] * i1;
    }
  }
}

extern "C" void kernel_launch(void* const* d_in, const int* in_sizes, int n_in,
                              void* d_out, int out_size, void* d_ws, size_t ws_size,
                              hipStream_t stream) {
  const float* x = (const float*)d_in[0];
  const float* wq = (const float*)d_in[1];
  const float* wk = (const float*)d_in[2];
  const float* wv = (const float*)d_in[3];
  float* out = (float*)d_out;
  char* ws = (char*)d_ws;

  // workspace layout; wqb/wkb/wvb are contiguous = W_all [3072][1024]
  bf16* xb  = (bf16*)(ws + 0);          // 16 MiB [8192][1024]
  bf16* wqb = (bf16*)(ws + 16777216);   // 2 MiB
  bf16* wkb = (bf16*)(ws + 18874368);   // 2 MiB
  bf16* wvb = (bf16*)(ws + 20971520);   // 2 MiB
  bf16* Qh  = (bf16*)(ws + 23068672);   // 16 MiB [B,H,S,D] (pre-scaled)
  bf16* Kh  = (bf16*)(ws + 39845888);   // 16 MiB [B,H,S,D]
  bf16* Vth = (bf16*)(ws + 56623104);   // 16 MiB [B,H,D,S]

  cast_all<<<11264, 256, 0, stream>>>(x, wq, wk, wv, (ushort*)xb, (ushort*)wqb,
                                      (ushort*)wkb, (ushort*)wvb);

  gemm_qkv_8ph<<<384, 512, 0, stream>>>(xb, wqb, Qh, Kh, Vth);

  attn_kernel<<<1024, 256, 0, stream>>>(Qh, Kh, Vth, out);
}